// Round 15
// baseline (44.327 us; speedup 1.0000x reference)
//
#include <hip/hip_runtime.h>

// LinearAutoDecoder: rgb[n, j] = dot(X[n, 0:63],  W_pos[3*cid[n]+j, :]) +
//                                dot(X[n, 63:127], W_feat[3*cid[n]+j, :])
//
// Quarter-wave (16 lanes) per point, 4 points/wave-iteration, 2-deep pipe.
// Dense X mapping: lane l16 covers features {4*l16..4*l16+3} and
// {64+4*l16..+3} (lane 15: shifted, junk slot has zero weight baked in).
// Weights: bf16 table Wt[c][3][16] uint4 (192 KiB in d_ws).
// This round: (1) k_pack widened to one uint4/thread (48 blocks, was 16);
// (2) X loads and out stores are NON-TEMPORAL so the streamed X doesn't
// evict the hot Wt table from L1 (weight bytes are the proven binder).

constexpr int ROWW = 127;   // 63 pos + 64 latent
constexpr int NC   = 256;   // clusters

typedef float f32x4v __attribute__((ext_vector_type(4), aligned(4)));

template <int CTRL, int RMASK, int BMASK>
__device__ __forceinline__ float dpp_add(float x) {
    int t = __builtin_amdgcn_update_dpp(0, __builtin_bit_cast(int, x),
                                        CTRL, RMASK, BMASK, false);
    return x + __builtin_bit_cast(float, t);
}

// Sum within each 16-lane row; full sum valid in lanes 12..15 of each row16.
__device__ __forceinline__ float row_sum(float x) {
    x = dpp_add<0xB1,  0xF, 0xF>(x);  // quad_perm xor1
    x = dpp_add<0x4E,  0xF, 0xF>(x);  // quad_perm xor2
    x = dpp_add<0x114, 0xF, 0xE>(x);  // row_shr:4  (banks 1-3)
    x = dpp_add<0x118, 0xF, 0xC>(x);  // row_shr:8  (banks 2-3)
    return x;
}

// Full-wave sum for the fallback kernel; valid in lane 63.
__device__ __forceinline__ float wave_sum63(float x) {
    x = row_sum(x);
    x = dpp_add<0x142, 0xA, 0xF>(x);  // row_bcast:15
    x = dpp_add<0x143, 0xC, 0xF>(x);  // row_bcast:31
    return x;
}

// bf16 helpers
__device__ __forceinline__ unsigned f2bf(float f) {      // RNE
    unsigned u = __builtin_bit_cast(unsigned, f);
    return (u + 0x7fffu + ((u >> 16) & 1u)) >> 16;
}
__device__ __forceinline__ float blo(unsigned u) {
    return __builtin_bit_cast(float, u << 16);
}
__device__ __forceinline__ float bhi(unsigned u) {
    return __builtin_bit_cast(float, u & 0xffff0000u);
}

__device__ __forceinline__ float wval(const float* Wp, const float* Wf,
                                      int r, int f) {
    if (f < 63)  return Wp[(size_t)r * 63 + f];
    if (f == 63) return Wf[(size_t)r * 64];
    if (f < 127) return Wf[(size_t)r * 64 + (f - 63)];
    return 0.0f;   // dead/junk features (>=127)
}

// ------- weight pack: Wt[c][3][16] uint4, dense-X pairing, 1 uint4/thread --
// lane l16 pairs: (4a,4a+1),(4a+2,4a+3) | l16<15: (b..b+3) b=64+4*l16
//                                        | l16==15: (124,125),(126,zero)

__global__ __launch_bounds__(256) void k_pack(const float* __restrict__ Wp,
                                              const float* __restrict__ Wf,
                                              uint4* __restrict__ Wt) {
    const int tid = blockIdx.x * 256 + threadIdx.x;   // 0 .. 12287
    const int c   = tid / 48;
    const int rem = tid - c * 48;
    const int j   = rem >> 4;
    const int l16 = rem & 15;
    const bool e15 = (l16 == 15);
    const int fa  = 4 * l16;
    const int fz  = e15 ? 124 : 64 + 4 * l16;
    const int fw  = e15 ? 126 : 64 + 4 * l16 + 2;
    const int fwh = e15 ? 128 : fw + 1;        // 128 -> wval = 0
    const int r = 3 * c + j;
    uint4 q;
    q.x = f2bf(wval(Wp, Wf, r, fa + 0)) | (f2bf(wval(Wp, Wf, r, fa + 1)) << 16);
    q.y = f2bf(wval(Wp, Wf, r, fa + 2)) | (f2bf(wval(Wp, Wf, r, fa + 3)) << 16);
    q.z = f2bf(wval(Wp, Wf, r, fz))     | (f2bf(wval(Wp, Wf, r, fz + 1)) << 16);
    q.w = f2bf(wval(Wp, Wf, r, fw))     | (f2bf(wval(Wp, Wf, r, fwh))    << 16);
    Wt[(size_t)(c * 3 + j) * 16 + l16] = q;
}

// dot of 8 x-values against one packed uint4 of 8 bf16 weights
__device__ __forceinline__ float dot8(const uint4& q,
                                      float x0, float x1, float x2, float x3,
                                      float x4, float x5, float x6, float x7) {
    return fmaf(x0, blo(q.x), x1 * bhi(q.x)) + fmaf(x2, blo(q.y), x3 * bhi(q.y))
         + fmaf(x4, blo(q.z), x5 * bhi(q.z)) + fmaf(x6, blo(q.w), x7 * bhi(q.w));
}

// compute + store one iteration from a register bank (non-temporal store)
__device__ __forceinline__ void comp_store(
    const f32x4v& v1, const f32x4v& v2, bool e15,
    const uint4& q0, const uint4& q1, const uint4& q2,
    float* __restrict__ out, int p, int l16)
{
    const float x0 = v1.x, x1 = v1.y, x2 = v1.z, x3 = v1.w;
    const float x4 = e15 ? v2.y : v2.x;   // lane15: features 124,125,126,junk
    const float x5 = e15 ? v2.z : v2.y;
    const float x6 = e15 ? v2.w : v2.z;
    const float x7 = e15 ? v2.x : v2.w;   // junk on lane15 (weight 0)

    float a0 = dot8(q0, x0, x1, x2, x3, x4, x5, x6, x7);
    float a1 = dot8(q1, x0, x1, x2, x3, x4, x5, x6, x7);
    float a2 = dot8(q2, x0, x1, x2, x3, x4, x5, x6, x7);

    a0 = row_sum(a0);
    a1 = row_sum(a1);
    a2 = row_sum(a2);

    const float sv = (l16 == 12) ? a0 : (l16 == 13) ? a1 : a2;
    if (l16 >= 12 && l16 < 15)
        __builtin_nontemporal_store(sv, out + 3 * (size_t)p + (l16 - 12));
}

// ---------------- main compute: 2-deep pipe, nbody even ----------------

__global__ __launch_bounds__(256, 8) void k_main_pipe2(
    const float* __restrict__ X,
    const int*   __restrict__ cid,
    const uint4* __restrict__ Wt,    // [256][3][16]
    float*       __restrict__ out,   // [N][3]
    int npts)
{
    const int lane = threadIdx.x & 63;
    const int l16  = lane & 15;
    const int qr   = lane >> 4;
    const bool e15 = (l16 == 15);
    const int off1 = 4 * l16;                  // features 4*l16..+3
    const int off2 = e15 ? 123 : 64 + 4 * l16; // dense second vector
    const int wid  = (blockIdx.x * blockDim.x + threadIdx.x) >> 6;
    const int nW   = (gridDim.x * blockDim.x) >> 6;
    const int step = nW * 4;
    const int last = npts - 1;
    const int nbody = npts / step;          // even and >= 2 by caller contract

    int p = wid * 4 + qr;

    // ---- prologue: bank A = iteration 0; c1 = cluster for iteration 1 ----
    f32x4v xa1, xa2;
    {
        const size_t base = (size_t)p * ROWW;
        xa1 = __builtin_nontemporal_load((const f32x4v*)(X + base + off1));
        xa2 = __builtin_nontemporal_load((const f32x4v*)(X + base + off2));
    }
    const int cA = cid[p];
    uint4 qa0, qa1, qa2;
    {
        const uint4* wb = Wt + (size_t)cA * 48 + l16;
        qa0 = wb[0]; qa1 = wb[16]; qa2 = wb[32];
    }
    int c1 = cid[min(p + step, last)];

    f32x4v xb1, xb2;
    uint4 qb0, qb1, qb2;

    for (int t = 0; t < nbody; t += 2) {
        // ======== body t: prefetch (t+1) into bank B, compute bank A ========
        {
            const uint4* wb = Wt + (size_t)c1 * 48 + l16;
            qb0 = wb[0]; qb1 = wb[16]; qb2 = wb[32];
        }
        const int c2 = cid[min(p + 2 * step, last)];
        {
            const size_t base = (size_t)min(p + step, last) * ROWW;
            xb1 = __builtin_nontemporal_load((const f32x4v*)(X + base + off1));
            xb2 = __builtin_nontemporal_load((const f32x4v*)(X + base + off2));
        }
        __builtin_amdgcn_sched_barrier(0);
        comp_store(xa1, xa2, e15, qa0, qa1, qa2, out, p, l16);

        // ======== body t+1: prefetch (t+2) into bank A, compute bank B ======
        {
            const uint4* wb = Wt + (size_t)c2 * 48 + l16;
            qa0 = wb[0]; qa1 = wb[16]; qa2 = wb[32];
        }
        c1 = cid[min(p + 3 * step, last)];
        {
            const size_t base = (size_t)min(p + 2 * step, last) * ROWW;
            xa1 = __builtin_nontemporal_load((const f32x4v*)(X + base + off1));
            xa2 = __builtin_nontemporal_load((const f32x4v*)(X + base + off2));
        }
        __builtin_amdgcn_sched_barrier(0);
        comp_store(xb1, xb2, e15, qb0, qb1, qb2, out, p + step, l16);

        p += 2 * step;
    }
}

// ---------------- generic quarter-wave kernel (any npts) ----------------

__global__ __launch_bounds__(256, 8) void k_main(
    const float* __restrict__ X,
    const int*   __restrict__ cid,
    const uint4* __restrict__ Wt,    // [256][3][16]
    float*       __restrict__ out,   // [N][3]
    int npts)
{
    const int lane = threadIdx.x & 63;
    const int l16  = lane & 15;
    const int qr   = lane >> 4;
    const bool e15 = (l16 == 15);
    const int off1 = 4 * l16;
    const int off2 = e15 ? 123 : 64 + 4 * l16;
    const int wid  = (blockIdx.x * blockDim.x + threadIdx.x) >> 6;
    const int nW   = (gridDim.x * blockDim.x) >> 6;
    const int step = nW * 4;
    const int last = npts - 1;
    const int niter = (npts + step - 1) / step;

    int p = wid * 4 + qr;
    int c = cid[min(p, last)];

    for (int t = 0; t < niter; ++t) {
        const size_t base = (size_t)min(p, last) * ROWW;
        const f32x4v xv1 = __builtin_nontemporal_load((const f32x4v*)(X + base + off1));
        const f32x4v xv2 = __builtin_nontemporal_load((const f32x4v*)(X + base + off2));

        const int pn = p + step;
        const int cn = cid[min(pn, last)];

        const uint4* wb = Wt + (size_t)c * 48 + l16;
        const uint4 q0 = wb[0];
        const uint4 q1 = wb[16];
        const uint4 q2 = wb[32];

        if (p < npts)
            comp_store(xv1, xv2, e15, q0, q1, q2, out, p, l16);

        p = pn; c = cn;
    }
}

// ---------------- fallback (ws too small): round-3 direct kernel ----------------

__global__ __launch_bounds__(256, 8) void lad_fallback(
    const float* __restrict__ X, const int* __restrict__ cid,
    const float* __restrict__ Wp, const float* __restrict__ Wf,
    float* __restrict__ out, int npts)
{
    const int lane  = threadIdx.x & 63;
    const int wid   = (blockIdx.x * blockDim.x + threadIdx.x) >> 6;
    const int nW    = (gridDim.x * blockDim.x) >> 6;
    const int lanec = (lane < 63) ? lane : 62;
    const bool l63  = (lane == 63);

    for (int n = wid; n < npts; n += 2 * nW) {
        const int n2 = n + nW;
        const bool has2 = (n2 < npts);

        const float* x0 = X + (size_t)n * ROWW;
        float xa0 = x0[lane];
        float xb0 = x0[63 + lane];
        int   c0  = __builtin_amdgcn_readfirstlane(cid[n]);

        float xa1 = 0.0f, xb1 = 0.0f;
        int   c1  = 0;
        if (has2) {
            const float* x1 = X + (size_t)n2 * ROWW;
            xa1 = x1[lane];
            xb1 = x1[63 + lane];
            c1  = __builtin_amdgcn_readfirstlane(cid[n2]);
        }
        if (l63) { xa0 = 0.0f; xa1 = 0.0f; }

        const float* wp0 = Wp + (size_t)(3 * c0) * 63;
        const float* wf0 = Wf + (size_t)(3 * c0) * 64;
        const float* wp1 = Wp + (size_t)(3 * c1) * 63;
        const float* wf1 = Wf + (size_t)(3 * c1) * 64;

        float a00 = fmaf(xa0, wp0[lanec],       xb0 * wf0[lane]);
        float a01 = fmaf(xa0, wp0[63 + lanec],  xb0 * wf0[64 + lane]);
        float a02 = fmaf(xa0, wp0[126 + lanec], xb0 * wf0[128 + lane]);
        float a10 = fmaf(xa1, wp1[lanec],       xb1 * wf1[lane]);
        float a11 = fmaf(xa1, wp1[63 + lanec],  xb1 * wf1[64 + lane]);
        float a12 = fmaf(xa1, wp1[126 + lanec], xb1 * wf1[128 + lane]);

        a00 = wave_sum63(a00); a01 = wave_sum63(a01); a02 = wave_sum63(a02);
        a10 = wave_sum63(a10); a11 = wave_sum63(a11); a12 = wave_sum63(a12);

        if (l63) {
            float* o0 = out + 3 * (size_t)n;
            o0[0] = a00; o0[1] = a01; o0[2] = a02;
            if (has2) {
                float* o1 = out + 3 * (size_t)n2;
                o1[0] = a10; o1[1] = a11; o1[2] = a12;
            }
        }
    }
}

extern "C" void kernel_launch(void* const* d_in, const int* in_sizes, int n_in,
                              void* d_out, int out_size, void* d_ws, size_t ws_size,
                              hipStream_t stream) {
    const float* X   = (const float*)d_in[0];
    const int*   cid = (const int*)d_in[1];
    const float* Wp  = (const float*)d_in[2];
    const float* Wf  = (const float*)d_in[3];
    float* out = (float*)d_out;
    const int npts = in_sizes[1];   // cluster_ids element count == N

    const size_t wt_bytes = (size_t)NC * 3 * 16 * sizeof(uint4);  // 192 KiB
    if (ws_size < wt_bytes) {
        dim3 grid(2048), block(256);
        hipLaunchKernelGGL(lad_fallback, grid, block, 0, stream,
                           X, cid, Wp, Wf, out, npts);
        return;
    }

    uint4* Wt = (uint4*)d_ws;
    hipLaunchKernelGGL(k_pack, dim3(NC * 3 * 16 / 256), dim3(256), 0, stream,
                       Wp, Wf, Wt);

    const int nW = (2048 * 256) >> 6;   // 8192 waves
    const int step = nW * 4;
    if (npts % (2 * step) == 0) {
        hipLaunchKernelGGL(k_main_pipe2, dim3(2048), dim3(256), 0, stream,
                           X, cid, Wt, out, npts);
    } else {
        hipLaunchKernelGGL(k_main, dim3(2048), dim3(256), 0, stream,
                           X, cid, Wt, out, npts);
    }
}

// Round 16
// 31.082 us; speedup vs baseline: 1.4262x; 1.4262x over previous
//
#include <hip/hip_runtime.h>

// LinearAutoDecoder: rgb[n, j] = dot(X[n, 0:63],  W_pos[3*cid[n]+j, :]) +
//                                dot(X[n, 63:127], W_feat[3*cid[n]+j, :])
//
// Quarter-wave (16 lanes) per point, 4 points/wave-iteration, 2-deep pipe.
// Dense X mapping: lane l16 covers features {4*l16..4*l16+3} and
// {64+4*l16..+3} (lane 15: shifted, junk slot has zero weight baked in).
// Weights: bf16 table Wt[c][3][16] uint4 (192 KiB in d_ws).
// r16: reverted r15's non-temporal hints (they cost X its ~45% L3 residency,
// +13us); kept the widened k_pack (one uint4/thread, 48 blocks).

constexpr int ROWW = 127;   // 63 pos + 64 latent
constexpr int NC   = 256;   // clusters

typedef float f32x4v __attribute__((ext_vector_type(4), aligned(4)));

template <int CTRL, int RMASK, int BMASK>
__device__ __forceinline__ float dpp_add(float x) {
    int t = __builtin_amdgcn_update_dpp(0, __builtin_bit_cast(int, x),
                                        CTRL, RMASK, BMASK, false);
    return x + __builtin_bit_cast(float, t);
}

// Sum within each 16-lane row; full sum valid in lanes 12..15 of each row16.
__device__ __forceinline__ float row_sum(float x) {
    x = dpp_add<0xB1,  0xF, 0xF>(x);  // quad_perm xor1
    x = dpp_add<0x4E,  0xF, 0xF>(x);  // quad_perm xor2
    x = dpp_add<0x114, 0xF, 0xE>(x);  // row_shr:4  (banks 1-3)
    x = dpp_add<0x118, 0xF, 0xC>(x);  // row_shr:8  (banks 2-3)
    return x;
}

// Full-wave sum for the fallback kernel; valid in lane 63.
__device__ __forceinline__ float wave_sum63(float x) {
    x = row_sum(x);
    x = dpp_add<0x142, 0xA, 0xF>(x);  // row_bcast:15
    x = dpp_add<0x143, 0xC, 0xF>(x);  // row_bcast:31
    return x;
}

// bf16 helpers
__device__ __forceinline__ unsigned f2bf(float f) {      // RNE
    unsigned u = __builtin_bit_cast(unsigned, f);
    return (u + 0x7fffu + ((u >> 16) & 1u)) >> 16;
}
__device__ __forceinline__ float blo(unsigned u) {
    return __builtin_bit_cast(float, u << 16);
}
__device__ __forceinline__ float bhi(unsigned u) {
    return __builtin_bit_cast(float, u & 0xffff0000u);
}

__device__ __forceinline__ float wval(const float* Wp, const float* Wf,
                                      int r, int f) {
    if (f < 63)  return Wp[(size_t)r * 63 + f];
    if (f == 63) return Wf[(size_t)r * 64];
    if (f < 127) return Wf[(size_t)r * 64 + (f - 63)];
    return 0.0f;   // dead/junk features (>=127)
}

// ------- weight pack: Wt[c][3][16] uint4, dense-X pairing, 1 uint4/thread --

__global__ __launch_bounds__(256) void k_pack(const float* __restrict__ Wp,
                                              const float* __restrict__ Wf,
                                              uint4* __restrict__ Wt) {
    const int tid = blockIdx.x * 256 + threadIdx.x;   // 0 .. 12287
    const int c   = tid / 48;
    const int rem = tid - c * 48;
    const int j   = rem >> 4;
    const int l16 = rem & 15;
    const bool e15 = (l16 == 15);
    const int fa  = 4 * l16;
    const int fz  = e15 ? 124 : 64 + 4 * l16;
    const int fw  = e15 ? 126 : 64 + 4 * l16 + 2;
    const int fwh = e15 ? 128 : fw + 1;        // 128 -> wval = 0
    const int r = 3 * c + j;
    uint4 q;
    q.x = f2bf(wval(Wp, Wf, r, fa + 0)) | (f2bf(wval(Wp, Wf, r, fa + 1)) << 16);
    q.y = f2bf(wval(Wp, Wf, r, fa + 2)) | (f2bf(wval(Wp, Wf, r, fa + 3)) << 16);
    q.z = f2bf(wval(Wp, Wf, r, fz))     | (f2bf(wval(Wp, Wf, r, fz + 1)) << 16);
    q.w = f2bf(wval(Wp, Wf, r, fw))     | (f2bf(wval(Wp, Wf, r, fwh))    << 16);
    Wt[(size_t)(c * 3 + j) * 16 + l16] = q;
}

// dot of 8 x-values against one packed uint4 of 8 bf16 weights
__device__ __forceinline__ float dot8(const uint4& q,
                                      float x0, float x1, float x2, float x3,
                                      float x4, float x5, float x6, float x7) {
    return fmaf(x0, blo(q.x), x1 * bhi(q.x)) + fmaf(x2, blo(q.y), x3 * bhi(q.y))
         + fmaf(x4, blo(q.z), x5 * bhi(q.z)) + fmaf(x6, blo(q.w), x7 * bhi(q.w));
}

// compute + store one iteration from a register bank
__device__ __forceinline__ void comp_store(
    const f32x4v& v1, const f32x4v& v2, bool e15,
    const uint4& q0, const uint4& q1, const uint4& q2,
    float* __restrict__ out, int p, int l16)
{
    const float x0 = v1.x, x1 = v1.y, x2 = v1.z, x3 = v1.w;
    const float x4 = e15 ? v2.y : v2.x;   // lane15: features 124,125,126,junk
    const float x5 = e15 ? v2.z : v2.y;
    const float x6 = e15 ? v2.w : v2.z;
    const float x7 = e15 ? v2.x : v2.w;   // junk on lane15 (weight 0)

    float a0 = dot8(q0, x0, x1, x2, x3, x4, x5, x6, x7);
    float a1 = dot8(q1, x0, x1, x2, x3, x4, x5, x6, x7);
    float a2 = dot8(q2, x0, x1, x2, x3, x4, x5, x6, x7);

    a0 = row_sum(a0);
    a1 = row_sum(a1);
    a2 = row_sum(a2);

    const float sv = (l16 == 12) ? a0 : (l16 == 13) ? a1 : a2;
    if (l16 >= 12 && l16 < 15)
        out[3 * (size_t)p + (l16 - 12)] = sv;
}

// ---------------- main compute: 2-deep pipe, nbody even ----------------

__global__ __launch_bounds__(256, 8) void k_main_pipe2(
    const float* __restrict__ X,
    const int*   __restrict__ cid,
    const uint4* __restrict__ Wt,    // [256][3][16]
    float*       __restrict__ out,   // [N][3]
    int npts)
{
    const int lane = threadIdx.x & 63;
    const int l16  = lane & 15;
    const int qr   = lane >> 4;
    const bool e15 = (l16 == 15);
    const int off1 = 4 * l16;                  // features 4*l16..+3
    const int off2 = e15 ? 123 : 64 + 4 * l16; // dense second vector
    const int wid  = (blockIdx.x * blockDim.x + threadIdx.x) >> 6;
    const int nW   = (gridDim.x * blockDim.x) >> 6;
    const int step = nW * 4;
    const int last = npts - 1;
    const int nbody = npts / step;          // even and >= 2 by caller contract

    int p = wid * 4 + qr;

    // ---- prologue: bank A = iteration 0; c1 = cluster for iteration 1 ----
    f32x4v xa1, xa2;
    {
        const size_t base = (size_t)p * ROWW;
        xa1 = *(const f32x4v*)(X + base + off1);
        xa2 = *(const f32x4v*)(X + base + off2);
    }
    const int cA = cid[p];
    uint4 qa0, qa1, qa2;
    {
        const uint4* wb = Wt + (size_t)cA * 48 + l16;
        qa0 = wb[0]; qa1 = wb[16]; qa2 = wb[32];
    }
    int c1 = cid[min(p + step, last)];

    f32x4v xb1, xb2;
    uint4 qb0, qb1, qb2;

    for (int t = 0; t < nbody; t += 2) {
        // ======== body t: prefetch (t+1) into bank B, compute bank A ========
        {
            const uint4* wb = Wt + (size_t)c1 * 48 + l16;
            qb0 = wb[0]; qb1 = wb[16]; qb2 = wb[32];
        }
        const int c2 = cid[min(p + 2 * step, last)];
        {
            const size_t base = (size_t)min(p + step, last) * ROWW;
            xb1 = *(const f32x4v*)(X + base + off1);
            xb2 = *(const f32x4v*)(X + base + off2);
        }
        __builtin_amdgcn_sched_barrier(0);
        comp_store(xa1, xa2, e15, qa0, qa1, qa2, out, p, l16);

        // ======== body t+1: prefetch (t+2) into bank A, compute bank B ======
        {
            const uint4* wb = Wt + (size_t)c2 * 48 + l16;
            qa0 = wb[0]; qa1 = wb[16]; qa2 = wb[32];
        }
        c1 = cid[min(p + 3 * step, last)];
        {
            const size_t base = (size_t)min(p + 2 * step, last) * ROWW;
            xa1 = *(const f32x4v*)(X + base + off1);
            xa2 = *(const f32x4v*)(X + base + off2);
        }
        __builtin_amdgcn_sched_barrier(0);
        comp_store(xb1, xb2, e15, qb0, qb1, qb2, out, p + step, l16);

        p += 2 * step;
    }
}

// ---------------- generic quarter-wave kernel (any npts) ----------------

__global__ __launch_bounds__(256, 8) void k_main(
    const float* __restrict__ X,
    const int*   __restrict__ cid,
    const uint4* __restrict__ Wt,    // [256][3][16]
    float*       __restrict__ out,   // [N][3]
    int npts)
{
    const int lane = threadIdx.x & 63;
    const int l16  = lane & 15;
    const int qr   = lane >> 4;
    const bool e15 = (l16 == 15);
    const int off1 = 4 * l16;
    const int off2 = e15 ? 123 : 64 + 4 * l16;
    const int wid  = (blockIdx.x * blockDim.x + threadIdx.x) >> 6;
    const int nW   = (gridDim.x * blockDim.x) >> 6;
    const int step = nW * 4;
    const int last = npts - 1;
    const int niter = (npts + step - 1) / step;

    int p = wid * 4 + qr;
    int c = cid[min(p, last)];

    for (int t = 0; t < niter; ++t) {
        const size_t base = (size_t)min(p, last) * ROWW;
        const f32x4v xv1 = *(const f32x4v*)(X + base + off1);
        const f32x4v xv2 = *(const f32x4v*)(X + base + off2);

        const int pn = p + step;
        const int cn = cid[min(pn, last)];

        const uint4* wb = Wt + (size_t)c * 48 + l16;
        const uint4 q0 = wb[0];
        const uint4 q1 = wb[16];
        const uint4 q2 = wb[32];

        if (p < npts)
            comp_store(xv1, xv2, e15, q0, q1, q2, out, p, l16);

        p = pn; c = cn;
    }
}

// ---------------- fallback (ws too small): round-3 direct kernel ----------------

__global__ __launch_bounds__(256, 8) void lad_fallback(
    const float* __restrict__ X, const int* __restrict__ cid,
    const float* __restrict__ Wp, const float* __restrict__ Wf,
    float* __restrict__ out, int npts)
{
    const int lane  = threadIdx.x & 63;
    const int wid   = (blockIdx.x * blockDim.x + threadIdx.x) >> 6;
    const int nW    = (gridDim.x * blockDim.x) >> 6;
    const int lanec = (lane < 63) ? lane : 62;
    const bool l63  = (lane == 63);

    for (int n = wid; n < npts; n += 2 * nW) {
        const int n2 = n + nW;
        const bool has2 = (n2 < npts);

        const float* x0 = X + (size_t)n * ROWW;
        float xa0 = x0[lane];
        float xb0 = x0[63 + lane];
        int   c0  = __builtin_amdgcn_readfirstlane(cid[n]);

        float xa1 = 0.0f, xb1 = 0.0f;
        int   c1  = 0;
        if (has2) {
            const float* x1 = X + (size_t)n2 * ROWW;
            xa1 = x1[lane];
            xb1 = x1[63 + lane];
            c1  = __builtin_amdgcn_readfirstlane(cid[n2]);
        }
        if (l63) { xa0 = 0.0f; xa1 = 0.0f; }

        const float* wp0 = Wp + (size_t)(3 * c0) * 63;
        const float* wf0 = Wf + (size_t)(3 * c0) * 64;
        const float* wp1 = Wp + (size_t)(3 * c1) * 63;
        const float* wf1 = Wf + (size_t)(3 * c1) * 64;

        float a00 = fmaf(xa0, wp0[lanec],       xb0 * wf0[lane]);
        float a01 = fmaf(xa0, wp0[63 + lanec],  xb0 * wf0[64 + lane]);
        float a02 = fmaf(xa0, wp0[126 + lanec], xb0 * wf0[128 + lane]);
        float a10 = fmaf(xa1, wp1[lanec],       xb1 * wf1[lane]);
        float a11 = fmaf(xa1, wp1[63 + lanec],  xb1 * wf1[64 + lane]);
        float a12 = fmaf(xa1, wp1[126 + lanec], xb1 * wf1[128 + lane]);

        a00 = wave_sum63(a00); a01 = wave_sum63(a01); a02 = wave_sum63(a02);
        a10 = wave_sum63(a10); a11 = wave_sum63(a11); a12 = wave_sum63(a12);

        if (l63) {
            float* o0 = out + 3 * (size_t)n;
            o0[0] = a00; o0[1] = a01; o0[2] = a02;
            if (has2) {
                float* o1 = out + 3 * (size_t)n2;
                o1[0] = a10; o1[1] = a11; o1[2] = a12;
            }
        }
    }
}

extern "C" void kernel_launch(void* const* d_in, const int* in_sizes, int n_in,
                              void* d_out, int out_size, void* d_ws, size_t ws_size,
                              hipStream_t stream) {
    const float* X   = (const float*)d_in[0];
    const int*   cid = (const int*)d_in[1];
    const float* Wp  = (const float*)d_in[2];
    const float* Wf  = (const float*)d_in[3];
    float* out = (float*)d_out;
    const int npts = in_sizes[1];   // cluster_ids element count == N

    const size_t wt_bytes = (size_t)NC * 3 * 16 * sizeof(uint4);  // 192 KiB
    if (ws_size < wt_bytes) {
        dim3 grid(2048), block(256);
        hipLaunchKernelGGL(lad_fallback, grid, block, 0, stream,
                           X, cid, Wp, Wf, out, npts);
        return;
    }

    uint4* Wt = (uint4*)d_ws;
    hipLaunchKernelGGL(k_pack, dim3(NC * 3 * 16 / 256), dim3(256), 0, stream,
                       Wp, Wf, Wt);

    const int nW = (2048 * 256) >> 6;   // 8192 waves
    const int step = nW * 4;
    if (npts % (2 * step) == 0) {
        hipLaunchKernelGGL(k_main_pipe2, dim3(2048), dim3(256), 0, stream,
                           X, cid, Wt, out, npts);
    } else {
        hipLaunchKernelGGL(k_main, dim3(2048), dim3(256), 0, stream,
                           X, cid, Wt, out, npts);
    }
}